// Round 17
// baseline (345.254 us; speedup 1.0000x reference)
//
#include <hip/hip_runtime.h>
#include <math.h>

// Problem constants
static constexpr int BB = 4;
static constexpr int NN = 16384;
static constexpr int KK = 8;
static constexpr int EE = 131072;   // edges per batch
static constexpr int RR = 65536;    // BB*NN rows
static constexpr int EG = 524288;   // total edges

// Stats: 64 planes x 512 floats per BN slot
static constexpr int SPL = 64;
static constexpr size_t SLOT = (size_t)SPL*512;

// Workspace layout (float offsets)
static constexpr size_t OFF_X0 = 0;
static constexpr size_t OFF_X1 = OFF_X0 + (size_t)RR*32;
static constexpr size_t OFF_X2 = OFF_X1 + (size_t)RR*64;
static constexpr size_t OFF_X3 = OFF_X2 + (size_t)RR*128;
static constexpr size_t OFF_ZB = OFF_X3 + (size_t)RR*256; // fp16 b-branch
static constexpr size_t OFF_ZC = OFF_ZB + (size_t)RR*128; // 65536 fp32
static constexpr size_t OFF_S  = OFF_ZC + (size_t)RR;     // 9 slots * SLOT
static constexpr size_t OFF_WP = OFF_S + 9*SLOT;          // packed fp16 weights
static constexpr size_t WP1_OFF = 0;
static constexpr size_t WP2_OFF = 4096;
static constexpr size_t WP3_OFF = 4096 + 16384;

__device__ __forceinline__ float lrelu(float x) { return fmaxf(x, 0.2f*x); }

__device__ __forceinline__ unsigned short f2h(float f) {
    _Float16 h = (_Float16)f;
    return *(unsigned short*)&h;
}
__device__ __forceinline__ float h2f(unsigned short u) {
    _Float16 h = *(_Float16*)&u;
    return (float)h;
}

typedef __attribute__((ext_vector_type(8))) _Float16 half8v;
typedef __attribute__((ext_vector_type(8))) unsigned short ushort8v;
typedef __attribute__((ext_vector_type(4))) float float4v;

// ---------------- layer 0: node GEMM 8->32 (pre-BN, fp16 out) + plane stats ----------------
__global__ __launch_bounds__(256) void k_l0_node(const float* __restrict__ xf,
                                                 const float* __restrict__ W,
                                                 unsigned short* __restrict__ z,
                                                 float* __restrict__ S) {
    __shared__ float w[256];
    __shared__ float red[64];
    int tid = threadIdx.x;
    w[tid] = W[tid];
    if (tid < 64) red[tid] = 0.f;
    __syncthreads();
    int r = blockIdx.x*256 + tid;
    const float4* xr = (const float4*)(xf + (size_t)r*8);
    float4 a = xr[0], b = xr[1];
    float xv[8] = {a.x,a.y,a.z,a.w,b.x,b.y,b.z,b.w};
    float op[32];
#pragma unroll
    for (int c = 0; c < 32; ++c) {
        float s = 0.f;
#pragma unroll
        for (int k = 0; k < 8; ++k) s = fmaf(xv[k], w[k*32+c], s);
        op[c] = s;
    }
    ushort8v* zp = (ushort8v*)(z + (size_t)r*32);
#pragma unroll
    for (int i = 0; i < 4; ++i) {
        ushort8v h;
#pragma unroll
        for (int j = 0; j < 8; ++j) h[j] = f2h(op[i*8+j]);
        zp[i] = h;
    }
#pragma unroll
    for (int c = 0; c < 32; ++c) {
        float s = op[c], q = op[c]*op[c];
#pragma unroll
        for (int off = 32; off >= 1; off >>= 1) {
            s += __shfl_xor(s, off, 64);
            q += __shfl_xor(q, off, 64);
        }
        if ((tid & 63) == 0) { atomicAdd(&red[c], s); atomicAdd(&red[32+c], q); }
    }
    __syncthreads();
    if (tid < 64) atomicAdd(&S[(size_t)(blockIdx.x & (SPL-1))*512 + tid], red[tid]);
}

// ---------------- layer 0 edge MLP: stats pass (plane flush) ----------------
__global__ __launch_bounds__(256) void k_edge_stats(const float* __restrict__ xf,
                                                    const int* __restrict__ ei,
                                                    const float* __restrict__ W,
                                                    float* __restrict__ S) {
    __shared__ float w[256];
    __shared__ float red[64];
    int tid = threadIdx.x;
    w[tid] = W[tid];
    if (tid < 64) red[tid] = 0.f;
    __syncthreads();
    float s[32], q[32];
#pragma unroll
    for (int c = 0; c < 32; ++c) { s[c] = 0.f; q[c] = 0.f; }
    for (int e = blockIdx.x*256 + tid; e < EG; e += gridDim.x*256) {
        int b = e >> 17, j = e & (EE-1);
        const int* base = ei + (size_t)b*2*EE;
        int ctr = base[j], nbr = base[EE + j];
        const float4* pc = (const float4*)(xf + ((size_t)(b<<14) + ctr)*8);
        const float4* pn = (const float4*)(xf + ((size_t)(b<<14) + nbr)*8);
        float4 c0 = pc[0], c1 = pc[1], n0 = pn[0], n1 = pn[1];
        float d[8] = {n0.x-c0.x, n0.y-c0.y, n0.z-c0.z, n0.w-c0.w,
                      n1.x-c1.x, n1.y-c1.y, n1.z-c1.z, n1.w-c1.w};
#pragma unroll
        for (int c = 0; c < 32; ++c) {
            float z = 0.f;
#pragma unroll
            for (int k = 0; k < 8; ++k) z = fmaf(d[k], w[k*32+c], z);
            s[c] += z; q[c] = fmaf(z, z, q[c]);
        }
    }
#pragma unroll
    for (int off = 32; off >= 1; off >>= 1) {
#pragma unroll
        for (int c = 0; c < 32; ++c) {
            s[c] += __shfl_xor(s[c], off, 64);
            q[c] += __shfl_xor(q[c], off, 64);
        }
    }
    if ((tid & 63) == 0) {
#pragma unroll
        for (int c = 0; c < 32; ++c) { atomicAdd(&red[c], s[c]); atomicAdd(&red[32+c], q[c]); }
    }
    __syncthreads();
    if (tid < 64) atomicAdd(&S[(size_t)(blockIdx.x & (SPL-1))*512 + tid], red[tid]);
}

// ---- layer 0 edge apply: BN finalize + BNa+lrelu + edge MLP max -> x0 fp16,
// plus zc[r] = dot(x0_final, Wc[0:32]) ----
__global__ __launch_bounds__(256) void k_edge_apply(const float* __restrict__ xf,
                                                    const int* __restrict__ ei,
                                                    const float* __restrict__ W,
                                                    const float* __restrict__ Sa,
                                                    const float* __restrict__ Sb,
                                                    const float* __restrict__ ga,
                                                    const float* __restrict__ ba,
                                                    const float* __restrict__ gb,
                                                    const float* __restrict__ bbp,
                                                    const float* __restrict__ Wc,
                                                    unsigned short* __restrict__ x0,
                                                    float* __restrict__ zc) {
    __shared__ float w[256];
    __shared__ float scb[32], shb[32], sca[32], sha[32], swc[32];
    int tid = threadIdx.x;
    w[tid] = W[tid];
    if (tid < 32) {
        float su = 0.f, qu = 0.f;
        for (int p = 0; p < SPL; ++p) { su += Sa[(size_t)p*512 + tid]; qu += Sa[(size_t)p*512 + 32 + tid]; }
        float m = su*(1.f/RR);
        float v = fmaxf(qu*(1.f/RR) - m*m, 0.f);
        float sc = ga[tid]*rsqrtf(v + 1e-5f);
        sca[tid] = sc; sha[tid] = fmaf(-m, sc, ba[tid]);
        swc[tid] = Wc[tid];
    } else if (tid < 64) {
        int c = tid - 32;
        float su = 0.f, qu = 0.f;
        for (int p = 0; p < SPL; ++p) { su += Sb[(size_t)p*512 + c]; qu += Sb[(size_t)p*512 + 32 + c]; }
        float m = su*(1.f/EG);
        float v = fmaxf(qu*(1.f/EG) - m*m, 0.f);
        float sc = gb[c]*rsqrtf(v + 1e-5f);
        scb[c] = sc; shb[c] = fmaf(-m, sc, bbp[c]);
    }
    __syncthreads();
    int r = blockIdx.x*256 + tid;
    int b = r >> 14, n = r & (NN-1);
    const int* nb = ei + (size_t)b*2*EE + EE + n*KK;
    const float4* pc = (const float4*)(xf + (size_t)r*8);
    float4 c0 = pc[0], c1 = pc[1];
    float mx[32];
#pragma unroll
    for (int c = 0; c < 32; ++c) mx[c] = -3.0e38f;
    for (int k = 0; k < KK; ++k) {
        int j = nb[k];
        const float4* pn = (const float4*)(xf + ((size_t)(b<<14) + j)*8);
        float4 n0 = pn[0], n1 = pn[1];
        float d[8] = {n0.x-c0.x, n0.y-c0.y, n0.z-c0.z, n0.w-c0.w,
                      n1.x-c1.x, n1.y-c1.y, n1.z-c1.z, n1.w-c1.w};
#pragma unroll
        for (int c = 0; c < 32; ++c) {
            float z = 0.f;
#pragma unroll
            for (int k2 = 0; k2 < 8; ++k2) z = fmaf(d[k2], w[k2*32+c], z);
            float y = lrelu(fmaf(z, scb[c], shb[c]));
            mx[c] = fmaxf(mx[c], y);
        }
    }
    ushort8v* xp = (ushort8v*)(x0 + (size_t)r*32);
    float sdot = 0.f;
#pragma unroll
    for (int i = 0; i < 4; ++i) {
        ushort8v v = xp[i];
        ushort8v o;
#pragma unroll
        for (int j = 0; j < 8; ++j) {
            int c = i*8 + j;
            float val = lrelu(fmaf(h2f(v[j]), sca[c], sha[c])) + mx[c];
            o[j] = f2h(val);
            sdot = fmaf(val, swc[c], sdot);
        }
        xp[i] = o;
    }
    zc[r] = sdot;
}

// ---- weight prep: pack Wa|Wb into MFMA fragment order ----
template<int CI, int CO>
__global__ __launch_bounds__(256) void k_packW(const float* __restrict__ Wa,
                                               const float* __restrict__ Wb,
                                               unsigned short* __restrict__ Wp) {
    constexpr int NT = 2*CO;
    constexpr int KT = CI/32;
    int t = blockIdx.x*256 + threadIdx.x;
    if (t >= NT*CI) return;
    int ng = t % NT, k = t / NT;
    float v = (ng < CO) ? Wa[(size_t)k*CO + ng] : Wb[(size_t)k*CO + (ng - CO)];
    int nt = ng >> 4, n = ng & 15;
    int kt = k >> 5, kq = (k & 31) >> 3, j = k & 7;
    int f = nt*KT + kt;
    int idx = f*512 + ((kq*16 + n)<<3) + j;
    Wp[idx] = f2h(v);
}

// ---- dual MFMA GEMM: A=W (LDS), B=X (direct global, chunk-major planes).
// Outputs CHUNK-MAJOR [plane][row][64]. MR=4: 64-row tile/wave.
template<int CI, int CO, int NCH, int MR>
__global__ __launch_bounds__(256, 4) void k_mfma_dual(const unsigned short* __restrict__ X,
                                                      const unsigned short* __restrict__ Wp,
                                                      unsigned short* __restrict__ Za,
                                                      unsigned short* __restrict__ Zb,
                                                      float* __restrict__ Sa,
                                                      float* __restrict__ Sb) {
    constexpr int KT = CI/32;
    constexpr int WCNT = NCH*KT*512;
    constexpr int ROWT = RR/(MR*16);
    constexpr int STR = NCH*16 + 8;
    constexpr int XW  = (CI < 64) ? CI : 64;
    constexpr int PLB = CO/64;
    __shared__ unsigned short Wlds[WCNT];
    __shared__ unsigned short scr[4][16*STR];
    int tid = threadIdx.x;
    int lane = tid & 63, wid = tid >> 6;
    int ch = blockIdx.y;
    int wglob = blockIdx.x*4 + wid;
    int NW = gridDim.x*4;
    int n = lane & 15, kq = lane >> 4;
    int rg = lane >> 3, c8l = (lane & 7)*8;
    unsigned short* myscr = scr[wid];
    size_t pl = (size_t)(wglob & (SPL-1)) * 512;
    bool isA = (ch < PLB);
    unsigned short* Zp = (isA ? Za : Zb) + (size_t)(isA ? ch : ch - PLB)*((size_t)RR*64);
    {
        const ushort8v* src = (const ushort8v*)(Wp + (size_t)ch*WCNT);
        ushort8v* dst = (ushort8v*)Wlds;
        for (int u = tid; u < WCNT/8; u += 256) dst[u] = src[u];
    }
    __syncthreads();

    for (int t = wglob; t < ROWT; t += NW) {
        size_t rowbase = (size_t)t * (MR*16);
        float4v acc[MR][NCH];
#pragma unroll
        for (int i = 0; i < MR; ++i)
#pragma unroll
            for (int j = 0; j < NCH; ++j)
                acc[i][j] = (float4v){0.f, 0.f, 0.f, 0.f};
#pragma unroll
        for (int kt = 0; kt < KT; ++kt) {
            int k0 = kt*32 + kq*8;
            int xpl = k0 >> 6;
            int xoff = k0 & (XW-1);
            const unsigned short* Xp = X + (size_t)xpl*((size_t)RR*64);
            half8v b[MR];
#pragma unroll
            for (int i = 0; i < MR; ++i)
                b[i] = *(const half8v*)&Xp[(rowbase + i*16 + n)*XW + xoff];
#pragma unroll
            for (int j = 0; j < NCH; ++j) {
                half8v w = *(const half8v*)&Wlds[(j*KT + kt)*512 + lane*8];
#pragma unroll
                for (int i = 0; i < MR; ++i)
                    acc[i][j] = __builtin_amdgcn_mfma_f32_16x16x32_f16(w, b[i], acc[i][j], 0, 0, 0);
            }
        }
#pragma unroll
        for (int j = 0; j < NCH; ++j) {
            int colg = ch*64 + j*16;
            float* Sg = isA ? Sa : Sb;
            int cb = isA ? colg : colg - CO;
#pragma unroll
            for (int reg = 0; reg < 4; ++reg) {
                float s = 0.f, q = 0.f;
#pragma unroll
                for (int i = 0; i < MR; ++i) {
                    float v = acc[i][j][reg];
                    s += v; q = fmaf(v, v, q);
                }
                s += __shfl_xor(s, 1, 64); q += __shfl_xor(q, 1, 64);
                s += __shfl_xor(s, 2, 64); q += __shfl_xor(q, 2, 64);
                s += __shfl_xor(s, 4, 64); q += __shfl_xor(q, 4, 64);
                s += __shfl_xor(s, 8, 64); q += __shfl_xor(q, 8, 64);
                if (n == 0) {
                    int col = cb + kq*4 + reg;
                    atomicAdd(&Sg[pl + col], s);
                    atomicAdd(&Sg[pl + CO + col], q);
                }
            }
        }
#pragma unroll
        for (int i = 0; i < MR; ++i) {
            __builtin_amdgcn_wave_barrier();
#pragma unroll
            for (int j = 0; j < NCH; ++j) {
                float4v a4 = acc[i][j];
                ushort4 h = { f2h(a4[0]), f2h(a4[1]), f2h(a4[2]), f2h(a4[3]) };
                *(ushort4*)&myscr[n*STR + j*16 + kq*4] = h;
            }
            __builtin_amdgcn_wave_barrier();
#pragma unroll
            for (int i2 = 0; i2 < 2; ++i2) {
                int rit = rg + i2*8;
                ushort8v v = *(const ushort8v*)&myscr[rit*STR + c8l];
                *(ushort8v*)&Zp[(rowbase + i*16 + rit)*64 + c8l] = v;
            }
        }
    }
}

// ---- fold 64 stat planes into plane 0 for both BN slots of a layer ----
template<int CO>
__global__ __launch_bounds__(256) void k_redstats(float* __restrict__ Sa,
                                                  float* __restrict__ Sb) {
    int t = blockIdx.x*256 + threadIdx.x;
    for (int u = t; u < 2*CO; u += gridDim.x*256) {
        float sa = 0.f, sb = 0.f;
        for (int p = 1; p < SPL; ++p) {
            sa += Sa[(size_t)p*512 + u];
            sb += Sb[(size_t)p*512 + u];
        }
        Sa[u] += sa;
        Sb[u] += sb;
    }
}

// ---- fused: BN finalize + BNa+lrelu center + gather-max(BNb+lrelu) + add (chunk-major)
// + cat contribution. XCD-aware swizzle: XCD pair -> one batch (L2 locality).
// WRITEBACK=false for the last layer (x3 is dead after the cat dot).
template<int CO, bool WRITEBACK>
__global__ __launch_bounds__(256) void k_gathermax(unsigned short* __restrict__ xi,
                                                   const unsigned short* __restrict__ zbh,
                                                   const int* __restrict__ ei,
                                                   const float* __restrict__ Sa,
                                                   const float* __restrict__ Sb,
                                                   const float* __restrict__ ga,
                                                   const float* __restrict__ ba,
                                                   const float* __restrict__ gb,
                                                   const float* __restrict__ bbp,
                                                   const float* __restrict__ Wc,
                                                   int wcoff,
                                                   float* __restrict__ zc) {
    constexpr int CQ = CO/8;
    constexpr int RPB = 256/CQ;   // rows per block
    __shared__ float sca[CO], sha[CO], scb[CO], shb[CO], swc[CO];
    int tid = threadIdx.x;
    for (int u = tid; u < CO; u += 256) {
        float m = Sa[u]*(1.f/RR);
        float v = fmaxf(Sa[CO+u]*(1.f/RR) - m*m, 0.f);
        float sc = ga[u]*rsqrtf(v + 1e-5f);
        sca[u] = sc; sha[u] = fmaf(-m, sc, ba[u]);
        m = Sb[u]*(1.f/RR);
        v = fmaxf(Sb[CO+u]*(1.f/RR) - m*m, 0.f);
        sc = gb[u]*rsqrtf(v + 1e-5f);
        scb[u] = sc; shb[u] = fmaf(-m, sc, bbp[u]);
        swc[u] = Wc[wcoff + u];
    }
    __syncthreads();
    // XCD swizzle: block i -> XCD (i&7); batch = xcd>>1; slot = (i>>3)*2 + (xcd&1)
    int i = blockIdx.x;
    int xcd = i & 7;
    int bt = xcd >> 1;
    int jj = ((i >> 3) << 1) + (xcd & 1);
    int r = bt*NN + jj*RPB + tid/CQ;
    int c8 = (tid % CQ)*8;
    int pln = c8 >> 6;
    int off = c8 & 63;
    const unsigned short* zpl = zbh + (size_t)pln*((size_t)RR*64);
    unsigned short* xpl = xi + (size_t)pln*((size_t)RR*64);
    int b = bt, n = r & (NN-1);
    const int* nb = ei + (size_t)b*2*EE + EE + n*KK;
    float sb[8], hb[8];
#pragma unroll
    for (int j = 0; j < 8; ++j) { sb[j] = scb[c8+j]; hb[j] = shb[c8+j]; }
    int nbr[KK];
#pragma unroll
    for (int k = 0; k < KK; ++k) nbr[k] = nb[k];
    size_t bb64 = ((size_t)(b<<14))*64 + off;
    float mx[8];
#pragma unroll
    for (int j = 0; j < 8; ++j) mx[j] = -3e38f;
#pragma unroll
    for (int k = 0; k < KK; ++k) {
        ushort8v u = *(const ushort8v*)(zpl + bb64 + (size_t)nbr[k]*64);
#pragma unroll
        for (int j = 0; j < 8; ++j)
            mx[j] = fmaxf(mx[j], lrelu(fmaf(h2f(u[j]), sb[j], hb[j])));
    }
    ushort8v* xp = (ushort8v*)&xpl[(size_t)r*64 + off];
    ushort8v a = *xp;
    float sdot = 0.f;
    if (WRITEBACK) {
        ushort8v o;
#pragma unroll
        for (int j = 0; j < 8; ++j) {
            float val = lrelu(fmaf(h2f(a[j]), sca[c8+j], sha[c8+j])) + mx[j];
            o[j] = f2h(val);
            sdot = fmaf(val, swc[c8+j], sdot);
        }
        *xp = o;
    } else {
#pragma unroll
        for (int j = 0; j < 8; ++j) {
            float val = lrelu(fmaf(h2f(a[j]), sca[c8+j], sha[c8+j])) + mx[j];
            sdot = fmaf(val, swc[c8+j], sdot);
        }
    }
#pragma unroll
    for (int w = CQ/2; w >= 1; w >>= 1) sdot += __shfl_xor(sdot, w, 64);
    int lane = tid & 63;
    if ((lane & (CQ-1)) == 0) atomicAdd(&zc[r], sdot);
}

// ---- cat head stats: sum/sumsq of zc into 256 plane-pairs ----
__global__ __launch_bounds__(256) void k_catstats(const float* __restrict__ zc,
                                                  float* __restrict__ S8) {
    __shared__ float rs2[2];
    int tid = threadIdx.x;
    if (tid < 2) rs2[tid] = 0.f;
    __syncthreads();
    float v = zc[blockIdx.x*256 + tid];
    float s = v, q = v*v;
#pragma unroll
    for (int off = 32; off >= 1; off >>= 1) {
        s += __shfl_xor(s, off, 64);
        q += __shfl_xor(q, off, 64);
    }
    if ((tid & 63) == 0) { atomicAdd(&rs2[0], s); atomicAdd(&rs2[1], q); }
    __syncthreads();
    if (tid == 0) {
        int p = blockIdx.x & 255;
        atomicAdd(&S8[p*2],     rs2[0]);
        atomicAdd(&S8[p*2 + 1], rs2[1]);
    }
}

// ---- final: reduce 256 plane-pairs, BN(1 col) + leaky + bias ----
__global__ __launch_bounds__(256) void k_catfinal(const float* __restrict__ zc,
                                                  const float* __restrict__ S8,
                                                  const float* __restrict__ g,
                                                  const float* __restrict__ bb,
                                                  const float* __restrict__ bias,
                                                  float* __restrict__ out) {
    __shared__ float rs[256], rq[256];
    int tid = threadIdx.x;
    rs[tid] = S8[tid*2];
    rq[tid] = S8[tid*2 + 1];
    __syncthreads();
#pragma unroll
    for (int h = 128; h >= 1; h >>= 1) {
        if (tid < h) { rs[tid] += rs[tid+h]; rq[tid] += rq[tid+h]; }
        __syncthreads();
    }
    int r = blockIdx.x*256 + tid;
    const float invR = 1.f/65536.f;
    float m = rs[0]*invR;
    float v = fmaxf(rq[0]*invR - m*m, 0.f);
    float sc = g[0]*rsqrtf(v + 1e-5f);
    float sh = fmaf(-m, sc, bb[0]);
    float y = lrelu(fmaf(zc[r], sc, sh));
    out[r] = y + bias[0];
}

extern "C" void kernel_launch(void* const* d_in, const int* in_sizes, int n_in,
                              void* d_out, int out_size, void* d_ws, size_t ws_size,
                              hipStream_t stream) {
    const float* x    = (const float*)d_in[0];
    const int*   ei   = (const int*)d_in[1];
    const float* W0a  = (const float*)d_in[2];
    const float* g0a  = (const float*)d_in[3];
    const float* b0a  = (const float*)d_in[4];
    const float* W0b  = (const float*)d_in[5];
    const float* g0b  = (const float*)d_in[6];
    const float* b0b  = (const float*)d_in[7];
    const float* W1a  = (const float*)d_in[8];
    const float* g1a  = (const float*)d_in[9];
    const float* b1a  = (const float*)d_in[10];
    const float* W1b  = (const float*)d_in[11];
    const float* g1b  = (const float*)d_in[12];
    const float* b1b  = (const float*)d_in[13];
    const float* W2a  = (const float*)d_in[14];
    const float* g2a  = (const float*)d_in[15];
    const float* b2a  = (const float*)d_in[16];
    const float* W2b  = (const float*)d_in[17];
    const float* g2b  = (const float*)d_in[18];
    const float* b2b  = (const float*)d_in[19];
    const float* W3a  = (const float*)d_in[20];
    const float* g3a  = (const float*)d_in[21];
    const float* b3a  = (const float*)d_in[22];
    const float* W3b  = (const float*)d_in[23];
    const float* g3b  = (const float*)d_in[24];
    const float* b3b  = (const float*)d_in[25];
    const float* Wcat = (const float*)d_in[26];
    const float* gcat = (const float*)d_in[27];
    const float* bcat = (const float*)d_in[28];
    const float* bias = (const float*)d_in[29];
    float* out = (float*)d_out;

    float* ws = (float*)d_ws;
    unsigned short* x0 = (unsigned short*)(ws + OFF_X0);
    unsigned short* x1 = (unsigned short*)(ws + OFF_X1);
    unsigned short* x2 = (unsigned short*)(ws + OFF_X2);
    unsigned short* x3 = (unsigned short*)(ws + OFF_X3);
    unsigned short* zbh = (unsigned short*)(ws + OFF_ZB);
    float* zc = ws + OFF_ZC;
    float* S  = ws + OFF_S;
    unsigned short* wpbase = (unsigned short*)(ws + OFF_WP);
    unsigned short* wp1 = wpbase + WP1_OFF;
    unsigned short* wp2 = wpbase + WP2_OFF;
    unsigned short* wp3 = wpbase + WP3_OFF;
    auto Sl = [&](int i) { return S + (size_t)i*SLOT; };

    hipMemsetAsync(S, 0, 9*SLOT*sizeof(float), stream);

    // ---- weight prep ----
    k_packW<32,64><<<(128*32+255)/256, 256, 0, stream>>>(W1a, W1b, wp1);
    k_packW<64,128><<<(256*64+255)/256, 256, 0, stream>>>(W2a, W2b, wp2);
    k_packW<128,256><<<(512*128+255)/256, 256, 0, stream>>>(W3a, W3b, wp3);

    // ---- layer 0 ----
    k_l0_node<<<RR/256, 256, 0, stream>>>(x, W0a, x0, Sl(0));
    k_edge_stats<<<1024, 256, 0, stream>>>(x, ei, W0b, Sl(1));
    k_edge_apply<<<RR/256, 256, 0, stream>>>(x, ei, W0b, Sl(0), Sl(1),
                                             g0a, b0a, g0b, b0b, Wcat, x0, zc);

    // ---- layer 1: 32 -> 64 (NCH=4 -> 2 chunks, MR=4) ----
    k_mfma_dual<32,64,4,4><<<dim3(256,2), 256, 0, stream>>>(x0, wp1, x1, zbh, Sl(2), Sl(3));
    k_redstats<64><<<4, 256, 0, stream>>>(Sl(2), Sl(3));
    k_gathermax<64,true><<<RR*8/256, 256, 0, stream>>>(x1, zbh, ei, Sl(2), Sl(3),
                                                       g1a, b1a, g1b, b1b, Wcat, 32, zc);

    // ---- layer 2: 64 -> 128 (NCH=4 -> 4 chunks, MR=4) ----
    k_mfma_dual<64,128,4,4><<<dim3(256,4), 256, 0, stream>>>(x1, wp2, x2, zbh, Sl(4), Sl(5));
    k_redstats<128><<<4, 256, 0, stream>>>(Sl(4), Sl(5));
    k_gathermax<128,true><<<RR*16/256, 256, 0, stream>>>(x2, zbh, ei, Sl(4), Sl(5),
                                                         g2a, b2a, g2b, b2b, Wcat, 96, zc);

    // ---- layer 3: 128 -> 256 (NCH=4 -> 8 chunks, MR=4; no x3 write-back) ----
    k_mfma_dual<128,256,4,4><<<dim3(256,8), 256, 0, stream>>>(x2, wp3, x3, zbh, Sl(6), Sl(7));
    k_redstats<256><<<4, 256, 0, stream>>>(Sl(6), Sl(7));
    k_gathermax<256,false><<<RR*32/256, 256, 0, stream>>>(x3, zbh, ei, Sl(6), Sl(7),
                                                          g3a, b3a, g3b, b3b, Wcat, 224, zc);

    // ---- cat head ----
    k_catstats<<<RR/256, 256, 0, stream>>>(zc, Sl(8));
    k_catfinal<<<RR/256, 256, 0, stream>>>(zc, Sl(8), gcat, bcat, bias, out);
}

// Round 18
// 312.171 us; speedup vs baseline: 1.1060x; 1.1060x over previous
//
#include <hip/hip_runtime.h>
#include <math.h>

// Problem constants
static constexpr int BB = 4;
static constexpr int NN = 16384;
static constexpr int KK = 8;
static constexpr int EE = 131072;   // edges per batch
static constexpr int RR = 65536;    // BB*NN rows
static constexpr int EG = 524288;   // total edges

// Stats: 64 planes x 512 floats per BN slot
static constexpr int SPL = 64;
static constexpr size_t SLOT = (size_t)SPL*512;

// Workspace layout (float offsets)
static constexpr size_t OFF_X0 = 0;
static constexpr size_t OFF_X1 = OFF_X0 + (size_t)RR*32;
static constexpr size_t OFF_X2 = OFF_X1 + (size_t)RR*64;
static constexpr size_t OFF_X3 = OFF_X2 + (size_t)RR*128;
static constexpr size_t OFF_ZB = OFF_X3 + (size_t)RR*256; // fp16 b-branch
static constexpr size_t OFF_ZC = OFF_ZB + (size_t)RR*128; // 65536 fp32
static constexpr size_t OFF_S  = OFF_ZC + (size_t)RR;     // 9 slots * SLOT
static constexpr size_t OFF_WP = OFF_S + 9*SLOT;          // packed fp16 weights
static constexpr size_t WP1_OFF = 0;
static constexpr size_t WP2_OFF = 4096;
static constexpr size_t WP3_OFF = 4096 + 16384;

__device__ __forceinline__ float lrelu(float x) { return fmaxf(x, 0.2f*x); }

__device__ __forceinline__ unsigned short f2h(float f) {
    _Float16 h = (_Float16)f;
    return *(unsigned short*)&h;
}
__device__ __forceinline__ float h2f(unsigned short u) {
    _Float16 h = *(_Float16*)&u;
    return (float)h;
}

typedef __attribute__((ext_vector_type(8))) _Float16 half8v;
typedef __attribute__((ext_vector_type(8))) unsigned short ushort8v;
typedef __attribute__((ext_vector_type(4))) float float4v;

// ---------------- layer 0: node GEMM 8->32 (pre-BN, fp16 out) + plane stats ----------------
__global__ __launch_bounds__(256) void k_l0_node(const float* __restrict__ xf,
                                                 const float* __restrict__ W,
                                                 unsigned short* __restrict__ z,
                                                 float* __restrict__ S) {
    __shared__ float w[256];
    __shared__ float red[64];
    int tid = threadIdx.x;
    w[tid] = W[tid];
    if (tid < 64) red[tid] = 0.f;
    __syncthreads();
    int r = blockIdx.x*256 + tid;
    const float4* xr = (const float4*)(xf + (size_t)r*8);
    float4 a = xr[0], b = xr[1];
    float xv[8] = {a.x,a.y,a.z,a.w,b.x,b.y,b.z,b.w};
    float op[32];
#pragma unroll
    for (int c = 0; c < 32; ++c) {
        float s = 0.f;
#pragma unroll
        for (int k = 0; k < 8; ++k) s = fmaf(xv[k], w[k*32+c], s);
        op[c] = s;
    }
    ushort8v* zp = (ushort8v*)(z + (size_t)r*32);
#pragma unroll
    for (int i = 0; i < 4; ++i) {
        ushort8v h;
#pragma unroll
        for (int j = 0; j < 8; ++j) h[j] = f2h(op[i*8+j]);
        zp[i] = h;
    }
#pragma unroll
    for (int c = 0; c < 32; ++c) {
        float s = op[c], q = op[c]*op[c];
#pragma unroll
        for (int off = 32; off >= 1; off >>= 1) {
            s += __shfl_xor(s, off, 64);
            q += __shfl_xor(q, off, 64);
        }
        if ((tid & 63) == 0) { atomicAdd(&red[c], s); atomicAdd(&red[32+c], q); }
    }
    __syncthreads();
    if (tid < 64) atomicAdd(&S[(size_t)(blockIdx.x & (SPL-1))*512 + tid], red[tid]);
}

// ---- layer 0 edge MLP stats: quad-split (4 lanes share an edge, 8 cols each) ----
__global__ __launch_bounds__(256) void k_edge_stats(const float* __restrict__ xf,
                                                    const int* __restrict__ ei,
                                                    const float* __restrict__ W,
                                                    float* __restrict__ S) {
    __shared__ float w[256];
    __shared__ float red[64];
    int tid = threadIdx.x;
    w[tid] = W[tid];
    if (tid < 64) red[tid] = 0.f;
    __syncthreads();
    int g = tid & 3;          // col group
    int cg = g*8;
    float s[8], q[8];
#pragma unroll
    for (int j = 0; j < 8; ++j) { s[j] = 0.f; q[j] = 0.f; }
    int qid = (blockIdx.x*256 + tid) >> 2;
    int NQ = (gridDim.x*256) >> 2;
    for (int e = qid; e < EG; e += NQ) {
        int b = e >> 17, jj = e & (EE-1);
        const int* base = ei + (size_t)b*2*EE;
        int ctr = base[jj], nbr = base[EE + jj];
        const float4* pc = (const float4*)(xf + ((size_t)(b<<14) + ctr)*8);
        const float4* pn = (const float4*)(xf + ((size_t)(b<<14) + nbr)*8);
        float4 c0 = pc[0], c1 = pc[1], n0 = pn[0], n1 = pn[1];
        float d[8] = {n0.x-c0.x, n0.y-c0.y, n0.z-c0.z, n0.w-c0.w,
                      n1.x-c1.x, n1.y-c1.y, n1.z-c1.z, n1.w-c1.w};
#pragma unroll
        for (int j = 0; j < 8; ++j) {
            int c = cg + j;
            float z = 0.f;
#pragma unroll
            for (int k = 0; k < 8; ++k) z = fmaf(d[k], w[k*32+c], z);
            s[j] += z; q[j] = fmaf(z, z, q[j]);
        }
    }
    // reduce across the 16 lanes sharing this col group (xor 4,8,16,32 keeps lane&3)
#pragma unroll
    for (int off = 4; off <= 32; off <<= 1) {
#pragma unroll
        for (int j = 0; j < 8; ++j) {
            s[j] += __shfl_xor(s[j], off, 64);
            q[j] += __shfl_xor(q[j], off, 64);
        }
    }
    if ((tid & 63) < 4) {
#pragma unroll
        for (int j = 0; j < 8; ++j) {
            atomicAdd(&red[cg + j], s[j]);
            atomicAdd(&red[32 + cg + j], q[j]);
        }
    }
    __syncthreads();
    if (tid < 64) atomicAdd(&S[(size_t)(blockIdx.x & (SPL-1))*512 + tid], red[tid]);
}

// ---- layer 0 edge apply: BN finalize + BNa+lrelu + edge MLP max -> x0 fp16,
// plus zc[r] = dot(x0_final, Wc[0:32]) ----
__global__ __launch_bounds__(256) void k_edge_apply(const float* __restrict__ xf,
                                                    const int* __restrict__ ei,
                                                    const float* __restrict__ W,
                                                    const float* __restrict__ Sa,
                                                    const float* __restrict__ Sb,
                                                    const float* __restrict__ ga,
                                                    const float* __restrict__ ba,
                                                    const float* __restrict__ gb,
                                                    const float* __restrict__ bbp,
                                                    const float* __restrict__ Wc,
                                                    unsigned short* __restrict__ x0,
                                                    float* __restrict__ zc) {
    __shared__ float w[256];
    __shared__ float scb[32], shb[32], sca[32], sha[32], swc[32];
    int tid = threadIdx.x;
    w[tid] = W[tid];
    if (tid < 32) {
        float su = 0.f, qu = 0.f;
        for (int p = 0; p < SPL; ++p) { su += Sa[(size_t)p*512 + tid]; qu += Sa[(size_t)p*512 + 32 + tid]; }
        float m = su*(1.f/RR);
        float v = fmaxf(qu*(1.f/RR) - m*m, 0.f);
        float sc = ga[tid]*rsqrtf(v + 1e-5f);
        sca[tid] = sc; sha[tid] = fmaf(-m, sc, ba[tid]);
        swc[tid] = Wc[tid];
    } else if (tid < 64) {
        int c = tid - 32;
        float su = 0.f, qu = 0.f;
        for (int p = 0; p < SPL; ++p) { su += Sb[(size_t)p*512 + c]; qu += Sb[(size_t)p*512 + 32 + c]; }
        float m = su*(1.f/EG);
        float v = fmaxf(qu*(1.f/EG) - m*m, 0.f);
        float sc = gb[c]*rsqrtf(v + 1e-5f);
        scb[c] = sc; shb[c] = fmaf(-m, sc, bbp[c]);
    }
    __syncthreads();
    int r = blockIdx.x*256 + tid;
    int b = r >> 14, n = r & (NN-1);
    const int* nb = ei + (size_t)b*2*EE + EE + n*KK;
    const float4* pc = (const float4*)(xf + (size_t)r*8);
    float4 c0 = pc[0], c1 = pc[1];
    float mx[32];
#pragma unroll
    for (int c = 0; c < 32; ++c) mx[c] = -3.0e38f;
    for (int k = 0; k < KK; ++k) {
        int j = nb[k];
        const float4* pn = (const float4*)(xf + ((size_t)(b<<14) + j)*8);
        float4 n0 = pn[0], n1 = pn[1];
        float d[8] = {n0.x-c0.x, n0.y-c0.y, n0.z-c0.z, n0.w-c0.w,
                      n1.x-c1.x, n1.y-c1.y, n1.z-c1.z, n1.w-c1.w};
#pragma unroll
        for (int c = 0; c < 32; ++c) {
            float z = 0.f;
#pragma unroll
            for (int k2 = 0; k2 < 8; ++k2) z = fmaf(d[k2], w[k2*32+c], z);
            float y = lrelu(fmaf(z, scb[c], shb[c]));
            mx[c] = fmaxf(mx[c], y);
        }
    }
    ushort8v* xp = (ushort8v*)(x0 + (size_t)r*32);
    float sdot = 0.f;
#pragma unroll
    for (int i = 0; i < 4; ++i) {
        ushort8v v = xp[i];
        ushort8v o;
#pragma unroll
        for (int j = 0; j < 8; ++j) {
            int c = i*8 + j;
            float val = lrelu(fmaf(h2f(v[j]), sca[c], sha[c])) + mx[c];
            o[j] = f2h(val);
            sdot = fmaf(val, swc[c], sdot);
        }
        xp[i] = o;
    }
    zc[r] = sdot;
}

// ---- weight prep: pack Wa|Wb into MFMA fragment order ----
template<int CI, int CO>
__global__ __launch_bounds__(256) void k_packW(const float* __restrict__ Wa,
                                               const float* __restrict__ Wb,
                                               unsigned short* __restrict__ Wp) {
    constexpr int NT = 2*CO;
    constexpr int KT = CI/32;
    int t = blockIdx.x*256 + threadIdx.x;
    if (t >= NT*CI) return;
    int ng = t % NT, k = t / NT;
    float v = (ng < CO) ? Wa[(size_t)k*CO + ng] : Wb[(size_t)k*CO + (ng - CO)];
    int nt = ng >> 4, n = ng & 15;
    int kt = k >> 5, kq = (k & 31) >> 3, j = k & 7;
    int f = nt*KT + kt;
    int idx = f*512 + ((kq*16 + n)<<3) + j;
    Wp[idx] = f2h(v);
}

// ---- dual MFMA GEMM: A=W (LDS), B=X (direct global, chunk-major planes).
// Outputs CHUNK-MAJOR [plane][row][64]. MR=4: 64-row tile/wave.
template<int CI, int CO, int NCH, int MR>
__global__ __launch_bounds__(256, 4) void k_mfma_dual(const unsigned short* __restrict__ X,
                                                      const unsigned short* __restrict__ Wp,
                                                      unsigned short* __restrict__ Za,
                                                      unsigned short* __restrict__ Zb,
                                                      float* __restrict__ Sa,
                                                      float* __restrict__ Sb) {
    constexpr int KT = CI/32;
    constexpr int WCNT = NCH*KT*512;
    constexpr int ROWT = RR/(MR*16);
    constexpr int STR = NCH*16 + 8;
    constexpr int XW  = (CI < 64) ? CI : 64;
    constexpr int PLB = CO/64;
    __shared__ unsigned short Wlds[WCNT];
    __shared__ unsigned short scr[4][16*STR];
    int tid = threadIdx.x;
    int lane = tid & 63, wid = tid >> 6;
    int ch = blockIdx.y;
    int wglob = blockIdx.x*4 + wid;
    int NW = gridDim.x*4;
    int n = lane & 15, kq = lane >> 4;
    int rg = lane >> 3, c8l = (lane & 7)*8;
    unsigned short* myscr = scr[wid];
    size_t pl = (size_t)(wglob & (SPL-1)) * 512;
    bool isA = (ch < PLB);
    unsigned short* Zp = (isA ? Za : Zb) + (size_t)(isA ? ch : ch - PLB)*((size_t)RR*64);
    {
        const ushort8v* src = (const ushort8v*)(Wp + (size_t)ch*WCNT);
        ushort8v* dst = (ushort8v*)Wlds;
        for (int u = tid; u < WCNT/8; u += 256) dst[u] = src[u];
    }
    __syncthreads();

    for (int t = wglob; t < ROWT; t += NW) {
        size_t rowbase = (size_t)t * (MR*16);
        float4v acc[MR][NCH];
#pragma unroll
        for (int i = 0; i < MR; ++i)
#pragma unroll
            for (int j = 0; j < NCH; ++j)
                acc[i][j] = (float4v){0.f, 0.f, 0.f, 0.f};
#pragma unroll
        for (int kt = 0; kt < KT; ++kt) {
            int k0 = kt*32 + kq*8;
            int xpl = k0 >> 6;
            int xoff = k0 & (XW-1);
            const unsigned short* Xp = X + (size_t)xpl*((size_t)RR*64);
            half8v b[MR];
#pragma unroll
            for (int i = 0; i < MR; ++i)
                b[i] = *(const half8v*)&Xp[(rowbase + i*16 + n)*XW + xoff];
#pragma unroll
            for (int j = 0; j < NCH; ++j) {
                half8v w = *(const half8v*)&Wlds[(j*KT + kt)*512 + lane*8];
#pragma unroll
                for (int i = 0; i < MR; ++i)
                    acc[i][j] = __builtin_amdgcn_mfma_f32_16x16x32_f16(w, b[i], acc[i][j], 0, 0, 0);
            }
        }
#pragma unroll
        for (int j = 0; j < NCH; ++j) {
            int colg = ch*64 + j*16;
            float* Sg = isA ? Sa : Sb;
            int cb = isA ? colg : colg - CO;
#pragma unroll
            for (int reg = 0; reg < 4; ++reg) {
                float s = 0.f, q = 0.f;
#pragma unroll
                for (int i = 0; i < MR; ++i) {
                    float v = acc[i][j][reg];
                    s += v; q = fmaf(v, v, q);
                }
                s += __shfl_xor(s, 1, 64); q += __shfl_xor(q, 1, 64);
                s += __shfl_xor(s, 2, 64); q += __shfl_xor(q, 2, 64);
                s += __shfl_xor(s, 4, 64); q += __shfl_xor(q, 4, 64);
                s += __shfl_xor(s, 8, 64); q += __shfl_xor(q, 8, 64);
                if (n == 0) {
                    int col = cb + kq*4 + reg;
                    atomicAdd(&Sg[pl + col], s);
                    atomicAdd(&Sg[pl + CO + col], q);
                }
            }
        }
#pragma unroll
        for (int i = 0; i < MR; ++i) {
            __builtin_amdgcn_wave_barrier();
#pragma unroll
            for (int j = 0; j < NCH; ++j) {
                float4v a4 = acc[i][j];
                ushort4 h = { f2h(a4[0]), f2h(a4[1]), f2h(a4[2]), f2h(a4[3]) };
                *(ushort4*)&myscr[n*STR + j*16 + kq*4] = h;
            }
            __builtin_amdgcn_wave_barrier();
#pragma unroll
            for (int i2 = 0; i2 < 2; ++i2) {
                int rit = rg + i2*8;
                ushort8v v = *(const ushort8v*)&myscr[rit*STR + c8l];
                *(ushort8v*)&Zp[(rowbase + i*16 + rit)*64 + c8l] = v;
            }
        }
    }
}

// ---- fold 64 stat planes into plane 0 for both BN slots of a layer ----
template<int CO>
__global__ __launch_bounds__(256) void k_redstats(float* __restrict__ Sa,
                                                  float* __restrict__ Sb) {
    int t = blockIdx.x*256 + threadIdx.x;
    for (int u = t; u < 2*CO; u += gridDim.x*256) {
        float sa = 0.f, sb = 0.f;
        for (int p = 1; p < SPL; ++p) {
            sa += Sa[(size_t)p*512 + u];
            sb += Sb[(size_t)p*512 + u];
        }
        Sa[u] += sa;
        Sb[u] += sb;
    }
}

// ---- fused: BN finalize + BNa+lrelu center + gather-max(BNb+lrelu) + add (chunk-major)
// + cat contribution. WRITEBACK=false for the last layer (x3 dead after the cat dot).
template<int CO, bool WRITEBACK>
__global__ __launch_bounds__(256) void k_gathermax(unsigned short* __restrict__ xi,
                                                   const unsigned short* __restrict__ zbh,
                                                   const int* __restrict__ ei,
                                                   const float* __restrict__ Sa,
                                                   const float* __restrict__ Sb,
                                                   const float* __restrict__ ga,
                                                   const float* __restrict__ ba,
                                                   const float* __restrict__ gb,
                                                   const float* __restrict__ bbp,
                                                   const float* __restrict__ Wc,
                                                   int wcoff,
                                                   float* __restrict__ zc) {
    constexpr int CQ = CO/8;
    __shared__ float sca[CO], sha[CO], scb[CO], shb[CO], swc[CO];
    int tid = threadIdx.x;
    for (int u = tid; u < CO; u += 256) {
        float m = Sa[u]*(1.f/RR);
        float v = fmaxf(Sa[CO+u]*(1.f/RR) - m*m, 0.f);
        float sc = ga[u]*rsqrtf(v + 1e-5f);
        sca[u] = sc; sha[u] = fmaf(-m, sc, ba[u]);
        m = Sb[u]*(1.f/RR);
        v = fmaxf(Sb[CO+u]*(1.f/RR) - m*m, 0.f);
        sc = gb[u]*rsqrtf(v + 1e-5f);
        scb[u] = sc; shb[u] = fmaf(-m, sc, bbp[u]);
        swc[u] = Wc[wcoff + u];
    }
    __syncthreads();
    int t = blockIdx.x*256 + tid;
    int r = t / CQ;
    int c8 = (t % CQ)*8;
    int pln = c8 >> 6;
    int off = c8 & 63;
    const unsigned short* zpl = zbh + (size_t)pln*((size_t)RR*64);
    unsigned short* xpl = xi + (size_t)pln*((size_t)RR*64);
    int b = r >> 14, n = r & (NN-1);
    const int* nb = ei + (size_t)b*2*EE + EE + n*KK;
    float sb[8], hb[8];
#pragma unroll
    for (int j = 0; j < 8; ++j) { sb[j] = scb[c8+j]; hb[j] = shb[c8+j]; }
    int nbr[KK];
#pragma unroll
    for (int k = 0; k < KK; ++k) nbr[k] = nb[k];
    size_t bb64 = ((size_t)(b<<14))*64 + off;
    float mx[8];
#pragma unroll
    for (int j = 0; j < 8; ++j) mx[j] = -3e38f;
#pragma unroll
    for (int k = 0; k < KK; ++k) {
        ushort8v u = *(const ushort8v*)(zpl + bb64 + (size_t)nbr[k]*64);
#pragma unroll
        for (int j = 0; j < 8; ++j)
            mx[j] = fmaxf(mx[j], lrelu(fmaf(h2f(u[j]), sb[j], hb[j])));
    }
    ushort8v* xp = (ushort8v*)&xpl[(size_t)r*64 + off];
    ushort8v a = *xp;
    float sdot = 0.f;
    if (WRITEBACK) {
        ushort8v o;
#pragma unroll
        for (int j = 0; j < 8; ++j) {
            float val = lrelu(fmaf(h2f(a[j]), sca[c8+j], sha[c8+j])) + mx[j];
            o[j] = f2h(val);
            sdot = fmaf(val, swc[c8+j], sdot);
        }
        *xp = o;
    } else {
#pragma unroll
        for (int j = 0; j < 8; ++j) {
            float val = lrelu(fmaf(h2f(a[j]), sca[c8+j], sha[c8+j])) + mx[j];
            sdot = fmaf(val, swc[c8+j], sdot);
        }
    }
#pragma unroll
    for (int w = CQ/2; w >= 1; w >>= 1) sdot += __shfl_xor(sdot, w, 64);
    int lane = tid & 63;
    if ((lane & (CQ-1)) == 0) atomicAdd(&zc[r], sdot);
}

// ---- cat head stats: sum/sumsq of zc into 256 plane-pairs ----
__global__ __launch_bounds__(256) void k_catstats(const float* __restrict__ zc,
                                                  float* __restrict__ S8) {
    __shared__ float rs2[2];
    int tid = threadIdx.x;
    if (tid < 2) rs2[tid] = 0.f;
    __syncthreads();
    float v = zc[blockIdx.x*256 + tid];
    float s = v, q = v*v;
#pragma unroll
    for (int off = 32; off >= 1; off >>= 1) {
        s += __shfl_xor(s, off, 64);
        q += __shfl_xor(q, off, 64);
    }
    if ((tid & 63) == 0) { atomicAdd(&rs2[0], s); atomicAdd(&rs2[1], q); }
    __syncthreads();
    if (tid == 0) {
        int p = blockIdx.x & 255;
        atomicAdd(&S8[p*2],     rs2[0]);
        atomicAdd(&S8[p*2 + 1], rs2[1]);
    }
}

// ---- final: reduce 256 plane-pairs, BN(1 col) + leaky + bias ----
__global__ __launch_bounds__(256) void k_catfinal(const float* __restrict__ zc,
                                                  const float* __restrict__ S8,
                                                  const float* __restrict__ g,
                                                  const float* __restrict__ bb,
                                                  const float* __restrict__ bias,
                                                  float* __restrict__ out) {
    __shared__ float rs[256], rq[256];
    int tid = threadIdx.x;
    rs[tid] = S8[tid*2];
    rq[tid] = S8[tid*2 + 1];
    __syncthreads();
#pragma unroll
    for (int h = 128; h >= 1; h >>= 1) {
        if (tid < h) { rs[tid] += rs[tid+h]; rq[tid] += rq[tid+h]; }
        __syncthreads();
    }
    int r = blockIdx.x*256 + tid;
    const float invR = 1.f/65536.f;
    float m = rs[0]*invR;
    float v = fmaxf(rq[0]*invR - m*m, 0.f);
    float sc = g[0]*rsqrtf(v + 1e-5f);
    float sh = fmaf(-m, sc, bb[0]);
    float y = lrelu(fmaf(zc[r], sc, sh));
    out[r] = y + bias[0];
}

extern "C" void kernel_launch(void* const* d_in, const int* in_sizes, int n_in,
                              void* d_out, int out_size, void* d_ws, size_t ws_size,
                              hipStream_t stream) {
    const float* x    = (const float*)d_in[0];
    const int*   ei   = (const int*)d_in[1];
    const float* W0a  = (const float*)d_in[2];
    const float* g0a  = (const float*)d_in[3];
    const float* b0a  = (const float*)d_in[4];
    const float* W0b  = (const float*)d_in[5];
    const float* g0b  = (const float*)d_in[6];
    const float* b0b  = (const float*)d_in[7];
    const float* W1a  = (const float*)d_in[8];
    const float* g1a  = (const float*)d_in[9];
    const float* b1a  = (const float*)d_in[10];
    const float* W1b  = (const float*)d_in[11];
    const float* g1b  = (const float*)d_in[12];
    const float* b1b  = (const float*)d_in[13];
    const float* W2a  = (const float*)d_in[14];
    const float* g2a  = (const float*)d_in[15];
    const float* b2a  = (const float*)d_in[16];
    const float* W2b  = (const float*)d_in[17];
    const float* g2b  = (const float*)d_in[18];
    const float* b2b  = (const float*)d_in[19];
    const float* W3a  = (const float*)d_in[20];
    const float* g3a  = (const float*)d_in[21];
    const float* b3a  = (const float*)d_in[22];
    const float* W3b  = (const float*)d_in[23];
    const float* g3b  = (const float*)d_in[24];
    const float* b3b  = (const float*)d_in[25];
    const float* Wcat = (const float*)d_in[26];
    const float* gcat = (const float*)d_in[27];
    const float* bcat = (const float*)d_in[28];
    const float* bias = (const float*)d_in[29];
    float* out = (float*)d_out;

    float* ws = (float*)d_ws;
    unsigned short* x0 = (unsigned short*)(ws + OFF_X0);
    unsigned short* x1 = (unsigned short*)(ws + OFF_X1);
    unsigned short* x2 = (unsigned short*)(ws + OFF_X2);
    unsigned short* x3 = (unsigned short*)(ws + OFF_X3);
    unsigned short* zbh = (unsigned short*)(ws + OFF_ZB);
    float* zc = ws + OFF_ZC;
    float* S  = ws + OFF_S;
    unsigned short* wpbase = (unsigned short*)(ws + OFF_WP);
    unsigned short* wp1 = wpbase + WP1_OFF;
    unsigned short* wp2 = wpbase + WP2_OFF;
    unsigned short* wp3 = wpbase + WP3_OFF;
    auto Sl = [&](int i) { return S + (size_t)i*SLOT; };

    hipMemsetAsync(S, 0, 9*SLOT*sizeof(float), stream);

    // ---- weight prep ----
    k_packW<32,64><<<(128*32+255)/256, 256, 0, stream>>>(W1a, W1b, wp1);
    k_packW<64,128><<<(256*64+255)/256, 256, 0, stream>>>(W2a, W2b, wp2);
    k_packW<128,256><<<(512*128+255)/256, 256, 0, stream>>>(W3a, W3b, wp3);

    // ---- layer 0 ----
    k_l0_node<<<RR/256, 256, 0, stream>>>(x, W0a, x0, Sl(0));
    k_edge_stats<<<512, 256, 0, stream>>>(x, ei, W0b, Sl(1));
    k_edge_apply<<<RR/256, 256, 0, stream>>>(x, ei, W0b, Sl(0), Sl(1),
                                             g0a, b0a, g0b, b0b, Wcat, x0, zc);

    // ---- layer 1: 32 -> 64 (NCH=4 -> 2 chunks, MR=4) ----
    k_mfma_dual<32,64,4,4><<<dim3(256,2), 256, 0, stream>>>(x0, wp1, x1, zbh, Sl(2), Sl(3));
    k_redstats<64><<<4, 256, 0, stream>>>(Sl(2), Sl(3));
    k_gathermax<64,true><<<RR*8/256, 256, 0, stream>>>(x1, zbh, ei, Sl(2), Sl(3),
                                                       g1a, b1a, g1b, b1b, Wcat, 32, zc);

    // ---- layer 2: 64 -> 128 (NCH=4 -> 4 chunks, MR=4) ----
    k_mfma_dual<64,128,4,4><<<dim3(256,4), 256, 0, stream>>>(x1, wp2, x2, zbh, Sl(4), Sl(5));
    k_redstats<128><<<4, 256, 0, stream>>>(Sl(4), Sl(5));
    k_gathermax<128,true><<<RR*16/256, 256, 0, stream>>>(x2, zbh, ei, Sl(4), Sl(5),
                                                         g2a, b2a, g2b, b2b, Wcat, 96, zc);

    // ---- layer 3: 128 -> 256 (NCH=4 -> 8 chunks, MR=4; no x3 write-back) ----
    k_mfma_dual<128,256,4,4><<<dim3(256,8), 256, 0, stream>>>(x2, wp3, x3, zbh, Sl(6), Sl(7));
    k_redstats<256><<<4, 256, 0, stream>>>(Sl(6), Sl(7));
    k_gathermax<256,false><<<RR*32/256, 256, 0, stream>>>(x3, zbh, ei, Sl(6), Sl(7),
                                                          g3a, b3a, g3b, b3b, Wcat, 224, zc);

    // ---- cat head ----
    k_catstats<<<RR/256, 256, 0, stream>>>(zc, Sl(8));
    k_catfinal<<<RR/256, 256, 0, stream>>>(zc, Sl(8), gcat, bcat, bias, out);
}